// Round 1
// baseline (1214.671 us; speedup 1.0000x reference)
//
#include <hip/hip_runtime.h>

#define HIDDEN 32
#define SORTK 30
#define SP_CAP 3072

static inline int ceil_div_i(long long a, int b){ return (int)((a + b - 1) / b); }

// ---------------- degree / dis ----------------
__global__ void count_kernel(const int* __restrict__ dsts, int* __restrict__ degcnt, int E){
  int e = blockIdx.x * blockDim.x + threadIdx.x;
  if (e < E) atomicAdd(&degcnt[dsts[e]], 1);
}

__global__ void dis_kernel(const int* __restrict__ degcnt, float* __restrict__ dis, int N){
  int n = blockIdx.x * blockDim.x + threadIdx.x;
  if (n < N){
    float d = (float)degcnt[n] + 1.0f;
    dis[n] = __fdiv_rn(1.0f, __fsqrt_rn(d));   // IEEE: matches 1/np.sqrt bitwise
  }
}

// ---------------- exclusive scan (3-kernel hierarchical) ----------------
__global__ void scanA(const int* __restrict__ in, int* __restrict__ bsum, int n){
  int i = blockIdx.x * 256 + threadIdx.x;
  int v = (i < n) ? in[i] : 0;
  for (int o = 32; o; o >>= 1) v += __shfl_down(v, o, 64);
  __shared__ int ws[4];
  int lane = threadIdx.x & 63, wid = threadIdx.x >> 6;
  if (lane == 0) ws[wid] = v;
  __syncthreads();
  if (threadIdx.x == 0) bsum[blockIdx.x] = ws[0] + ws[1] + ws[2] + ws[3];
}

// single block, 1024 threads; requires nb <= 1024 (nb = ceil(250000/256) = 977)
__global__ void scanB(int* __restrict__ bsum, int nb, int* __restrict__ offsets, int N){
  int tid = threadIdx.x;
  int v = (tid < nb) ? bsum[tid] : 0;
  int x = v;
  int lane = tid & 63, wid = tid >> 6;
  for (int o = 1; o < 64; o <<= 1){ int y = __shfl_up(x, o, 64); if (lane >= o) x += y; }
  __shared__ int wsum[16]; __shared__ int woff[16]; __shared__ int tot;
  if (lane == 63) wsum[wid] = x;
  __syncthreads();
  if (tid == 0){ int run = 0; for (int w = 0; w < 16; w++){ woff[w] = run; run += wsum[w]; } tot = run; }
  __syncthreads();
  if (tid < nb) bsum[tid] = x - v + woff[wid];
  if (tid == 0) offsets[N] = tot;   // = E
}

__global__ void scanC(const int* __restrict__ in, const int* __restrict__ boff,
                      int* __restrict__ offsets, int* __restrict__ cursor, int n){
  int i = blockIdx.x * 256 + threadIdx.x;
  int v = (i < n) ? in[i] : 0;
  int x = v;
  int lane = threadIdx.x & 63, wid = threadIdx.x >> 6;
  for (int o = 1; o < 64; o <<= 1){ int y = __shfl_up(x, o, 64); if (lane >= o) x += y; }
  __shared__ int wsum[4]; __shared__ int woff[4];
  if (lane == 63) wsum[wid] = x;
  __syncthreads();
  if (threadIdx.x == 0){ int run = 0; for (int w = 0; w < 4; w++){ woff[w] = run; run += wsum[w]; } }
  __syncthreads();
  if (i < n){ int e = x - v + woff[wid] + boff[blockIdx.x]; offsets[i] = e; cursor[i] = e; }
}

// ---------------- CSR build (sorted by (dst, edge-id) => deterministic, edge-order sums) ----
__global__ void fill_kernel(const int* __restrict__ dsts, int* __restrict__ cursor,
                            int* __restrict__ csr, int E){
  int e = blockIdx.x * blockDim.x + threadIdx.x;
  if (e < E){ int slot = atomicAdd(&cursor[dsts[e]], 1); csr[slot] = e; }
}

__global__ void sort_csr_kernel(const int* __restrict__ offsets, int* __restrict__ csr,
                                const int* __restrict__ srcs, int N){
  int n = blockIdx.x * blockDim.x + threadIdx.x;
  if (n >= N) return;
  int s = offsets[n], e = offsets[n + 1];
  for (int i = s + 1; i < e; i++){        // insertion sort (avg deg ~10)
    int key = csr[i]; int j = i - 1;
    while (j >= s && csr[j] > key){ csr[j + 1] = csr[j]; j--; }
    csr[j + 1] = key;
  }
  for (int i = s; i < e; i++) csr[i] = srcs[csr[i]];  // eid -> src, order preserved
}

// ---------------- per-node matmul h = x @ W ----------------
template<int K>
__global__ void node_matmul(const float* __restrict__ xin, const float* __restrict__ W,
                            float* __restrict__ H, int N){
  __shared__ float Ws[K * 32];
  for (int i = threadIdx.x; i < K * 32; i += blockDim.x) Ws[i] = W[i];
  __syncthreads();
  int tid = blockIdx.x * blockDim.x + threadIdx.x;
  int n = tid >> 5, c = tid & 31;
  if (n >= N) return;
  const float* xr = xin + (size_t)n * K;
  float acc = 0.f;
  #pragma unroll
  for (int k = 0; k < K; k++) acc = fmaf(xr[k], Ws[k * 32 + c], acc);
  H[(size_t)n * 32 + c] = acc;
}

// ---------------- GCN aggregation (deterministic, mirrors np op order) ----------------
__global__ void agg_kernel(const float* __restrict__ H, const int* __restrict__ offsets,
                           const int* __restrict__ csr, const float* __restrict__ dis,
                           const float* __restrict__ bias, float* __restrict__ A, int N){
  int tid = blockIdx.x * blockDim.x + threadIdx.x;
  int n = tid >> 5, c = tid & 31;
  if (n >= N) return;
  float dn = dis[n];
  int s = offsets[n], e = offsets[n + 1];
  float acc = 0.f;
  for (int i = s; i < e; i++){
    int sr = csr[i];
    float w = __fmul_rn(dis[sr], dn);                    // (dis[src]*dis[dst]) rounded
    acc = __fadd_rn(acc, __fmul_rn(H[(size_t)sr * 32 + c], w)); // msg rounded, then ordered add
  }
  float selfw = __fmul_rn(dn, dn);
  float v = __fadd_rn(acc, __fmul_rn(H[(size_t)n * 32 + c], selfw));
  v = __fadd_rn(v, bias[c]);
  A[(size_t)n * 32 + c] = fmaxf(v, 0.f);
}

// ---------------- graph boundaries (batch is sorted) ----------------
__global__ void gstarts_kernel(const int* __restrict__ batch, int* __restrict__ gstarts,
                               int N, int G){
  int g = blockIdx.x * blockDim.x + threadIdx.x;
  if (g > G) return;
  int lo = 0, hi = N;
  while (lo < hi){ int mid = (lo + hi) >> 1; if (batch[mid] < g) lo = mid + 1; else hi = mid; }
  gstarts[g] = lo;
}

// ---------------- sort-pool: stable top-30 by key desc, tie by index asc ----------------
__global__ void sort_pool_kernel(const float* __restrict__ A, const int* __restrict__ gstarts,
                                 float* __restrict__ pooled){
  int g = blockIdx.x;
  int s = gstarts[g], e = gstarts[g + 1];
  int c = e - s;
  __shared__ float keys[SP_CAP];
  bool uselds = (c <= SP_CAP);
  if (uselds){
    for (int i = threadIdx.x; i < c; i += blockDim.x) keys[i] = A[(size_t)(s + i) * 32 + 31];
  }
  __syncthreads();
  for (int i = threadIdx.x; i < c; i += blockDim.x){
    float ki = uselds ? keys[i] : A[(size_t)(s + i) * 32 + 31];
    int rank = 0; bool sel = true;
    for (int j = 0; j < c; j++){
      float kj = uselds ? keys[j] : A[(size_t)(s + j) * 32 + 31];
      if (kj > ki || (kj == ki && j < i)){
        if (++rank >= SORTK){ sel = false; break; }
      }
    }
    if (sel){
      // store transposed for conv: pooled[g][ch][pos]
      for (int ch = 0; ch < 32; ch++)
        pooled[(size_t)g * 32 * SORTK + ch * SORTK + rank] = A[(size_t)(s + i) * 32 + ch];
    }
  }
}

// ---------------- head: conv1 -> conv2 -> dense1 -> dense2, one block per graph ----------
__global__ __launch_bounds__(128) void head_kernel(
    const float* __restrict__ pooled,
    const float* __restrict__ cw1, const float* __restrict__ cb1,
    const float* __restrict__ cw2, const float* __restrict__ cb2,
    const float* __restrict__ lw1, const float* __restrict__ lb1,
    const float* __restrict__ lw2, const float* __restrict__ lb2,
    float* __restrict__ out){
  int g = blockIdx.x;
  int t = threadIdx.x;
  __shared__ float sin_[32 * 30];     // 960
  __shared__ float c1[16 * 26];       // 416
  __shared__ float c2[32 * 22];       // 704
  __shared__ float d1[128];
  __shared__ float w1s[16 * 32 * 5];  // 2560
  __shared__ float w2s[32 * 16 * 5];  // 2560

  for (int i = t; i < 960; i += 128)  sin_[i] = pooled[(size_t)g * 960 + i];
  for (int i = t; i < 2560; i += 128) w1s[i] = cw1[i];
  for (int i = t; i < 2560; i += 128) w2s[i] = cw2[i];
  __syncthreads();

  // conv1: (32,30) -> (16,26)
  for (int q = t; q < 16 * 26; q += 128){
    int o = q / 26, tt = q % 26;
    float acc = cb1[o];
    const float* wo = &w1s[o * 160];
    for (int i = 0; i < 32; i++){
      const float* si = &sin_[i * 30 + tt];
      #pragma unroll
      for (int k = 0; k < 5; k++) acc = fmaf(si[k], wo[i * 5 + k], acc);
    }
    c1[q] = fmaxf(acc, 0.f);
  }
  __syncthreads();

  // conv2: (16,26) -> (32,22)
  for (int q = t; q < 32 * 22; q += 128){
    int o = q / 22, tt = q % 22;
    float acc = cb2[o];
    const float* wo = &w2s[o * 80];
    for (int i = 0; i < 16; i++){
      const float* si = &c1[i * 26 + tt];
      #pragma unroll
      for (int k = 0; k < 5; k++) acc = fmaf(si[k], wo[i * 5 + k], acc);
    }
    c2[q] = fmaxf(acc, 0.f);
  }
  __syncthreads();

  // dense1: 704 -> 128 (thread t computes output t; lw1 reads coalesced)
  {
    float acc = lb1[t];
    for (int j = 0; j < 704; j++) acc = fmaf(c2[j], lw1[(size_t)j * 128 + t], acc);
    d1[t] = fmaxf(acc, 0.f);
  }
  __syncthreads();

  // dense2: 128 -> 1
  if (t == 0){
    float acc = lb2[0];
    for (int o = 0; o < 128; o++) acc = fmaf(d1[o], lw2[o], acc);
    out[g] = acc;
  }
}

// ---------------- launch ----------------
extern "C" void kernel_launch(void* const* d_in, const int* in_sizes, int n_in,
                              void* d_out, int out_size, void* d_ws, size_t ws_size,
                              hipStream_t stream){
  const float* x     = (const float*)d_in[0];
  const int*   ei    = (const int*)  d_in[1];
  const int*   batch = (const int*)  d_in[2];
  // d_in[3] = num_graphs scalar; we use out_size (== G)
  const float* W1  = (const float*)d_in[4];
  const float* b1  = (const float*)d_in[5];
  const float* W2  = (const float*)d_in[6];
  const float* b2  = (const float*)d_in[7];
  const float* W3  = (const float*)d_in[8];
  const float* b3  = (const float*)d_in[9];
  const float* cw1 = (const float*)d_in[10];
  const float* cb1 = (const float*)d_in[11];
  const float* cw2 = (const float*)d_in[12];
  const float* cb2 = (const float*)d_in[13];
  const float* lw1 = (const float*)d_in[14];
  const float* lb1 = (const float*)d_in[15];
  const float* lw2 = (const float*)d_in[16];
  const float* lb2 = (const float*)d_in[17];

  int N = in_sizes[0] / 9;
  int E = in_sizes[1] / 2;
  int G = out_size;
  const int* srcs = ei;
  const int* dsts = ei + E;

  char* base = (char*)d_ws;
  size_t off = 0;
  auto alloc = [&](size_t bytes) -> void* {
    off = (off + 255) & ~(size_t)255;
    void* r = base + off; off += bytes; return r;
  };
  float* dis    = (float*)alloc((size_t)N * 4);
  float* H      = (float*)alloc((size_t)N * 32 * 4);
  float* A      = (float*)alloc((size_t)N * 32 * 4);
  float* pooled = (float*)alloc((size_t)G * 32 * SORTK * 4);
  int*   degcnt = (int*)alloc((size_t)N * 4);
  int*   offs   = (int*)alloc((size_t)(N + 1) * 4);
  int*   cursor = (int*)alloc((size_t)N * 4);
  int*   csr    = (int*)alloc((size_t)E * 4);
  int*   bsum   = (int*)alloc((size_t)ceil_div_i(N, 256) * 4);
  int*   gst    = (int*)alloc((size_t)(G + 1) * 4);
  (void)ws_size; (void)n_in;

  hipMemsetAsync(degcnt, 0, (size_t)N * 4, stream);
  hipMemsetAsync(pooled, 0, (size_t)G * 32 * SORTK * 4, stream);

  int nb = ceil_div_i(N, 256);
  count_kernel<<<ceil_div_i(E, 256), 256, 0, stream>>>(dsts, degcnt, E);
  dis_kernel<<<nb, 256, 0, stream>>>(degcnt, dis, N);
  scanA<<<nb, 256, 0, stream>>>(degcnt, bsum, N);
  scanB<<<1, 1024, 0, stream>>>(bsum, nb, offs, N);
  scanC<<<nb, 256, 0, stream>>>(degcnt, bsum, offs, cursor, N);
  fill_kernel<<<ceil_div_i(E, 256), 256, 0, stream>>>(dsts, cursor, csr, E);
  sort_csr_kernel<<<nb, 256, 0, stream>>>(offs, csr, srcs, N);

  int nt = ceil_div_i((long long)N * 32, 256);
  node_matmul<9><<<nt, 256, 0, stream>>>(x, W1, H, N);
  agg_kernel<<<nt, 256, 0, stream>>>(H, offs, csr, dis, b1, A, N);
  node_matmul<32><<<nt, 256, 0, stream>>>(A, W2, H, N);
  agg_kernel<<<nt, 256, 0, stream>>>(H, offs, csr, dis, b2, A, N);
  node_matmul<32><<<nt, 256, 0, stream>>>(A, W3, H, N);
  agg_kernel<<<nt, 256, 0, stream>>>(H, offs, csr, dis, b3, A, N);

  gstarts_kernel<<<ceil_div_i(G + 1, 256), 256, 0, stream>>>(batch, gst, N, G);
  sort_pool_kernel<<<G, 128, 0, stream>>>(A, gst, pooled);
  head_kernel<<<G, 128, 0, stream>>>(pooled, cw1, cb1, cw2, cb2, lw1, lb1, lw2, lb2,
                                     (float*)d_out);
}